// Round 2
// baseline (183.821 us; speedup 1.0000x reference)
//
#include <hip/hip_runtime.h>

#define B_TOTAL 2097152
#define N_IN 7
#define HID 32

// tanh(x) = 1 - 2/(exp(2x)+1); exact at +-inf (rcp(inf)=0 -> 1; exp(-inf)=0 -> -1).
__device__ __forceinline__ float fast_tanh(float x) {
    float e = __expf(2.0f * x);                 // v_mul + v_exp_f32
    float r = __builtin_amdgcn_rcpf(e + 1.0f);  // v_add + v_rcp_f32 (~1 ulp)
    return __builtin_fmaf(-2.0f, r, 1.0f);      // v_fma
}

extern "C" __global__ void __launch_bounds__(256)
mlp_kernel(const float* __restrict__ q,
           const float* __restrict__ w0,
           const float* __restrict__ b0,
           const float* __restrict__ w1,
           const float* __restrict__ b1,
           const float* __restrict__ w2,
           const float* __restrict__ b2,
           float* __restrict__ out)
{
    const int i = blockIdx.x * blockDim.x + threadIdx.x;

    // Per-sample input into VGPRs.
    float x[N_IN];
#pragma unroll
    for (int k = 0; k < N_IN; ++k) x[k] = q[i * N_IN + k];

    // Layer 0: 7 -> 32, tanh. Weight indices are wave-uniform -> s_load.
    float z0[HID];
#pragma unroll
    for (int h = 0; h < HID; ++h) {
        float acc = b0[h];
#pragma unroll
        for (int k = 0; k < N_IN; ++k)
            acc = __builtin_fmaf(w0[h * N_IN + k], x[k], acc);
        z0[h] = fast_tanh(acc);
    }

    // Layer 1: 32 -> 32, tanh. 1024 FMAs, weights via SGPRs.
    float z1[HID];
#pragma unroll
    for (int h = 0; h < HID; ++h) {
        float acc = b1[h];
#pragma unroll
        for (int k = 0; k < HID; ++k)
            acc = __builtin_fmaf(w1[h * HID + k], z0[k], acc);
        z1[h] = fast_tanh(acc);
    }

    // Output layer: 32 -> 1 (no activation).
    float acc = b2[0];
#pragma unroll
    for (int k = 0; k < HID; ++k)
        acc = __builtin_fmaf(w2[k], z1[k], acc);

    out[i] = acc;
}

extern "C" void kernel_launch(void* const* d_in, const int* in_sizes, int n_in,
                              void* d_out, int out_size, void* d_ws, size_t ws_size,
                              hipStream_t stream) {
    const float* q  = (const float*)d_in[0];
    const float* w0 = (const float*)d_in[1];
    const float* b0 = (const float*)d_in[2];
    const float* w1 = (const float*)d_in[3];
    const float* b1 = (const float*)d_in[4];
    const float* w2 = (const float*)d_in[5];
    const float* b2 = (const float*)d_in[6];
    float* out = (float*)d_out;

    dim3 grid(B_TOTAL / 256), block(256);
    hipLaunchKernelGGL(mlp_kernel, grid, block, 0, stream,
                       q, w0, b0, w1, b1, w2, b2, out);
}

// Round 4
// 128.850 us; speedup vs baseline: 1.4266x; 1.4266x over previous
//
#include <hip/hip_runtime.h>

#define B_TOTAL 2097152
#define NBLK    1024
#define NWAVES  (NBLK * 4)
#define NTILES  (B_TOTAL / 64)

typedef _Float16 f16x8 __attribute__((ext_vector_type(8)));
typedef float    f32x16 __attribute__((ext_vector_type(16)));

union V4 { f16x8 v; unsigned u[4]; };

__device__ __forceinline__ unsigned pk(float lo, float hi) {
    return __builtin_bit_cast(unsigned, __builtin_amdgcn_cvt_pkrtz(lo, hi));
}

// tanh(x) = 1 - 2/(exp(2x)+1); exact at +-inf.
__device__ __forceinline__ float fast_tanh(float x) {
    float e = __expf(2.0f * x);
    float r = __builtin_amdgcn_rcpf(e + 1.0f);
    return __builtin_fmaf(-2.0f, r, 1.0f);
}

struct Consts {
    f16x8 a0, a1c0, a1c1;   // W0(+b0 ones-row) frag, W1 k-chunk frags
    float bias1v[16];       // b1[H(r,g)]
    float w2v[16];          // w2[H(r,g)]
};

// Evaluate one 32-sample tile. xw = packed f16 input words (k-pairs 01,23,45,6|one).
// Returns w2 . tanh(z1) partial-sum already reduced across the half-wave pair.
__device__ __forceinline__ float eval_tile(const unsigned xw[4], bool hi,
                                           const Consts& C) {
    // L0 B-operand: lanes g=0 supply k=0..7 (7 inputs + ones row), g=1 -> zero pad.
    V4 bx;
#pragma unroll
    for (int m = 0; m < 4; ++m) bx.u[m] = hi ? 0u : xw[m];

    f32x16 d;
#pragma unroll
    for (int r = 0; r < 16; ++r) d[r] = 0.0f;
    d = __builtin_amdgcn_mfma_f32_32x32x16_f16(C.a0, bx.v, d, 0, 0, 0);

    // tanh, pack h-pairs to f16. Lane holds h = (r&3)+8*(r>>2)+4g for sample l&31.
    float z[16];
#pragma unroll
    for (int r = 0; r < 16; ++r) z[r] = fast_tanh(d[r]);
    unsigned p[8], s[8];
#pragma unroll
    for (int j = 0; j < 8; ++j) p[j] = pk(z[2 * j], z[2 * j + 1]);
#pragma unroll
    for (int j = 0; j < 8; ++j) s[j] = __shfl_xor((int)p[j], 32);

    // Assemble L1 B-frags: lane needs z0 k-pairs {16c+8g+2m, +1}.
    // p_j holds pair base [0,2,8,10,16,18,24,26][j] + 4g; partner via s_j.
    V4 bf0, bf1;
    bf0.u[0] = hi ? s[2] : p[0];
    bf0.u[1] = hi ? s[3] : p[1];
    bf0.u[2] = hi ? p[2] : s[0];
    bf0.u[3] = hi ? p[3] : s[1];
    bf1.u[0] = hi ? s[6] : p[4];
    bf1.u[1] = hi ? s[7] : p[5];
    bf1.u[2] = hi ? p[6] : s[4];
    bf1.u[3] = hi ? p[7] : s[5];

    f32x16 e;
#pragma unroll
    for (int r = 0; r < 16; ++r) e[r] = C.bias1v[r];
    e = __builtin_amdgcn_mfma_f32_32x32x16_f16(C.a1c0, bf0.v, e, 0, 0, 0);
    e = __builtin_amdgcn_mfma_f32_32x32x16_f16(C.a1c1, bf1.v, e, 0, 0, 0);

    // L2: per-lane 16 h'-values, partner holds the other 16.
    float part = 0.0f;
#pragma unroll
    for (int r = 0; r < 16; ++r)
        part = __builtin_fmaf(C.w2v[r], fast_tanh(e[r]), part);
    part += __shfl_xor(part, 32);
    return part;
}

extern "C" __global__ void __launch_bounds__(256)
mlp_mfma(const float* __restrict__ q,  const float* __restrict__ w0,
         const float* __restrict__ b0, const float* __restrict__ w1,
         const float* __restrict__ b1, const float* __restrict__ w2,
         const float* __restrict__ b2, float* __restrict__ out)
{
    const int  l   = threadIdx.x & 63;
    const int  c5  = l & 31;
    const bool hi  = (l >= 32);
    const int  g   = hi ? 1 : 0;
    const int  wid = blockIdx.x * 4 + (threadIdx.x >> 6);

    Consts C;
    {   // A-frag L0: A[row=c5][k=8g+j]; row of W0 (7 cols) + b0 in k=7; g=1 zero.
        V4 t;
        if (!hi) {
            const float* wr = w0 + c5 * 7;
            t.u[0] = pk(wr[0], wr[1]);
            t.u[1] = pk(wr[2], wr[3]);
            t.u[2] = pk(wr[4], wr[5]);
            t.u[3] = pk(wr[6], b0[c5]);
        } else {
            t.u[0] = t.u[1] = t.u[2] = t.u[3] = 0u;
        }
        C.a0 = t.v;
    }
    {   // A-frags L1: A[row=c5][k=16c+8g+j] = w1[c5*32 + 16c + 8g + j]
        const float* wr = w1 + c5 * 32 + 8 * g;
        V4 t;
        t.u[0] = pk(wr[0], wr[1]);   t.u[1] = pk(wr[2], wr[3]);
        t.u[2] = pk(wr[4], wr[5]);   t.u[3] = pk(wr[6], wr[7]);
        C.a1c0 = t.v;
        t.u[0] = pk(wr[16], wr[17]); t.u[1] = pk(wr[18], wr[19]);
        t.u[2] = pk(wr[20], wr[21]); t.u[3] = pk(wr[22], wr[23]);
        C.a1c1 = t.v;
    }
#pragma unroll
    for (int r = 0; r < 16; ++r) {
        const int h = (r & 3) + 8 * (r >> 2) + 4 * g;
        C.bias1v[r] = b1[h];
        C.w2v[r]    = w2[h];
    }
    const float bias2 = b2[0];

    for (int tile = wid; tile < NTILES; tile += NWAVES) {
        const int base = tile * 64;
        // Each lane loads its own sample; tile0 = samples base+0..31 (data in
        // lanes 0..31), tile1 = base+32..63 (routed to lanes 0..31 via xor 32).
        const float* qp = q + (size_t)(base + l) * 7;
        float x[7];
#pragma unroll
        for (int k = 0; k < 7; ++k) x[k] = qp[k];
        unsigned xp[4] = { pk(x[0], x[1]), pk(x[2], x[3]),
                           pk(x[4], x[5]), pk(x[6], 1.0f) };
        unsigned xs[4];
#pragma unroll
        for (int m = 0; m < 4; ++m) xs[m] = __shfl_xor((int)xp[m], 32);

        float t0 = eval_tile(xp, hi, C);
        float t1 = eval_tile(xs, hi, C);
        // Lane l<32 holds sample base+l (tile0); lane l>=32 holds base+l (tile1).
        out[base + l] = (hi ? t1 : t0) + bias2;
    }
}

extern "C" void kernel_launch(void* const* d_in, const int* in_sizes, int n_in,
                              void* d_out, int out_size, void* d_ws, size_t ws_size,
                              hipStream_t stream) {
    const float* q  = (const float*)d_in[0];
    const float* w0 = (const float*)d_in[1];
    const float* b0 = (const float*)d_in[2];
    const float* w1 = (const float*)d_in[3];
    const float* b1 = (const float*)d_in[4];
    const float* w2 = (const float*)d_in[5];
    const float* b2 = (const float*)d_in[6];
    float* out = (float*)d_out;

    hipLaunchKernelGGL(mlp_mfma, dim3(NBLK), dim3(256), 0, stream,
                       q, w0, b0, w1, b1, w2, b2, out);
}

// Round 7
// 127.262 us; speedup vs baseline: 1.4444x; 1.0125x over previous
//
#include <hip/hip_runtime.h>

#define B_TOTAL 2097152
#define NBLK    2048
#define NWAVES  (NBLK * 4)
#define NTILES  (B_TOTAL / 64)

typedef _Float16 f16x8 __attribute__((ext_vector_type(8)));
typedef float    f32x16 __attribute__((ext_vector_type(16)));

union V4 { f16x8 v; unsigned u[4]; };

__device__ __forceinline__ unsigned pk(float lo, float hi) {
    return __builtin_bit_cast(unsigned, __builtin_amdgcn_cvt_pkrtz(lo, hi));
}

// tanh(x) = 1 - 2/(exp(2x)+1); exact at +-inf.
__device__ __forceinline__ float fast_tanh(float x) {
    float e = __expf(2.0f * x);
    float r = __builtin_amdgcn_rcpf(e + 1.0f);
    return __builtin_fmaf(-2.0f, r, 1.0f);
}

struct Consts {
    f16x8 a0lo, a0hi;     // W0+b0 frag: weights in g0 half (tile0) / g1 half (tile1)
    f16x8 a1c0, a1c1;     // W1 frags, COLUMN-PERMUTED so z0 needs no routing
    float bias1v[16];     // b1[h(r,g)]
    float w2v[16];        // w2[h(r,g)]
    float halfb2;         // 0.5*b2 (each half-wave partial carries one)
};

// One 32-sample tile. bxw = L0 B-operand words (own data or zero).
// Returns per-lane partial of w2 . tanh(z1) (+halfb2); pair-sum done by caller.
__device__ __forceinline__ float eval_tile(const f16x8 a0, const unsigned bxw[4],
                                           const Consts& C) {
    V4 bx;
#pragma unroll
    for (int m = 0; m < 4; ++m) bx.u[m] = bxw[m];

    f32x16 d;
#pragma unroll
    for (int r = 0; r < 16; ++r) d[r] = 0.0f;
    d = __builtin_amdgcn_mfma_f32_32x32x16_f16(a0, bx.v, d, 0, 0, 0);

    // Lane (g,c5) holds pre-act of h(r,g) = (r&3)+8*(r>>2)+4g for sample col c5.
    // tanh + pack pairs; words STAY in this lane (W1 frags absorb the permutation).
    unsigned p[8];
#pragma unroll
    for (int j = 0; j < 8; ++j)
        p[j] = pk(fast_tanh(d[2 * j]), fast_tanh(d[2 * j + 1]));

    V4 bf0, bf1;
#pragma unroll
    for (int m = 0; m < 4; ++m) { bf0.u[m] = p[m]; bf1.u[m] = p[4 + m]; }

    f32x16 e;
#pragma unroll
    for (int r = 0; r < 16; ++r) e[r] = C.bias1v[r];
    e = __builtin_amdgcn_mfma_f32_32x32x16_f16(C.a1c0, bf0.v, e, 0, 0, 0);
    e = __builtin_amdgcn_mfma_f32_32x32x16_f16(C.a1c1, bf1.v, e, 0, 0, 0);

    // L2 partial: this lane's 16 h'-values; partner half-wave holds the other 16.
    float part = C.halfb2;
#pragma unroll
    for (int r = 0; r < 16; ++r)
        part = __builtin_fmaf(C.w2v[r], fast_tanh(e[r]), part);
    return part;
}

extern "C" __global__ void __launch_bounds__(256)
mlp_mfma(const float* __restrict__ q,  const float* __restrict__ w0,
         const float* __restrict__ b0, const float* __restrict__ w1,
         const float* __restrict__ b1, const float* __restrict__ w2,
         const float* __restrict__ b2, float* __restrict__ out)
{
    const int  l   = threadIdx.x & 63;
    const int  c5  = l & 31;
    const bool hi  = (l >= 32);
    const int  g   = hi ? 1 : 0;
    const int  wid = blockIdx.x * 4 + (threadIdx.x >> 6);

    Consts C;
    {   // L0 A-frags: row c5 of W0 (7 cols) + b0 folded at k=7 (ones-row in B).
        // a0lo: weights live in g0 lanes (k=0..7), g1 zero -> consumes tile0 B.
        // a0hi: weights live in g1 lanes (k=8..15), g0 zero -> consumes tile1 B.
        const float* w0r = w0 + c5 * 7;
        V4 t, z;
        t.u[0] = pk(w0r[0], w0r[1]);
        t.u[1] = pk(w0r[2], w0r[3]);
        t.u[2] = pk(w0r[4], w0r[5]);
        t.u[3] = pk(w0r[6], b0[c5]);
        z.u[0] = z.u[1] = z.u[2] = z.u[3] = 0u;
        C.a0lo = hi ? z.v : t.v;
        C.a0hi = hi ? t.v : z.v;
    }
    {   // L1 A-frags with permuted columns: A_c[row=c5][slot=8g+j] =
        //   W1[c5][16c + 4g + (j&3) + 8*(j>>2)]
        // matching in-place z0 placement pi(8g+j) = 4g + (j&3) + 8*(j>>2).
        const float* wr = w1 + c5 * 32 + 4 * g;
        V4 t;
        t.u[0] = pk(wr[0], wr[1]);   t.u[1] = pk(wr[2],  wr[3]);
        t.u[2] = pk(wr[8], wr[9]);   t.u[3] = pk(wr[10], wr[11]);
        C.a1c0 = t.v;
        t.u[0] = pk(wr[16], wr[17]); t.u[1] = pk(wr[18], wr[19]);
        t.u[2] = pk(wr[24], wr[25]); t.u[3] = pk(wr[26], wr[27]);
        C.a1c1 = t.v;
    }
#pragma unroll
    for (int r = 0; r < 16; ++r) {
        const int h = (r & 3) + 8 * (r >> 2) + 4 * g;
        C.bias1v[r] = b1[h];
        C.w2v[r]    = w2[h];
    }
    C.halfb2 = 0.5f * b2[0];

#pragma unroll 1
    for (int tile = wid; tile < NTILES; tile += NWAVES) {
        const int base = tile * 64;
        // Each lane loads ITS OWN sample and supplies it to its own column:
        // tile0 = samples base+0..31 (g0 lanes), tile1 = base+32..63 (g1 lanes).
        const float* qp = q + (size_t)(base + l) * 7;
        float x[7];
#pragma unroll
        for (int k = 0; k < 7; ++k) x[k] = qp[k];
        unsigned xp[4] = { pk(x[0], x[1]), pk(x[2], x[3]),
                           pk(x[4], x[5]), pk(x[6], 1.0f) };

        unsigned bx0[4], bx1[4];
#pragma unroll
        for (int m = 0; m < 4; ++m) {
            bx0[m] = hi ? 0u : xp[m];   // tile0 B: g0 supplies k=0..7, g1 pad
            bx1[m] = hi ? xp[m] : 0u;   // tile1 B: g1 supplies k=8..15, g0 pad
        }

        float p0 = eval_tile(C.a0lo, bx0, C);
        float p1 = eval_tile(C.a0hi, bx1, C);

        // Pair-sum: keep own tile's partial, hand the other to the partner.
        // g0 lane c5 needs p0@g1 (partner sends p0); g1 needs p1@g0.
        float keep = hi ? p1 : p0;
        float send = hi ? p0 : p1;
        out[base + l] = keep + __shfl_xor(send, 32);
    }
}

extern "C" void kernel_launch(void* const* d_in, const int* in_sizes, int n_in,
                              void* d_out, int out_size, void* d_ws, size_t ws_size,
                              hipStream_t stream) {
    const float* q  = (const float*)d_in[0];
    const float* w0 = (const float*)d_in[1];
    const float* b0 = (const float*)d_in[2];
    const float* w1 = (const float*)d_in[3];
    const float* b1 = (const float*)d_in[4];
    const float* w2 = (const float*)d_in[5];
    const float* b2 = (const float*)d_in[6];
    float* out = (float*)d_out;

    hipLaunchKernelGGL(mlp_mfma, dim3(NBLK), dim3(256), 0, stream,
                       q, w0, b0, w1, b1, w2, b2, out);
}

// Round 8
// 126.648 us; speedup vs baseline: 1.4514x; 1.0048x over previous
//
#include <hip/hip_runtime.h>

#define B_TOTAL 2097152
#define NBLK    2048
#define NWAVES  (NBLK * 4)
#define NTILES  (B_TOTAL / 64)
#define ITERS   (NTILES / NWAVES)   // = 4, exact

typedef _Float16 f16x8 __attribute__((ext_vector_type(8)));
typedef float    f32x16 __attribute__((ext_vector_type(16)));

union V4 { f16x8 v; unsigned u[4]; };

static __device__ __forceinline__ unsigned pk(float lo, float hi) {
    return __builtin_bit_cast(unsigned, __builtin_amdgcn_cvt_pkrtz(lo, hi));
}

// tanh(x) = 1 - 2/(exp(2x)+1); exact at +-inf.
static __device__ __forceinline__ float fast_tanh(float x) {
    float e = __expf(2.0f * x);
    float r = __builtin_amdgcn_rcpf(e + 1.0f);
    return __builtin_fmaf(-2.0f, r, 1.0f);
}

// One 32-sample tile. All state passed as scalars/vectors -> registers only.
static __device__ __forceinline__ float
eval_tile(f16x8 a0, unsigned b0w, unsigned b1w, unsigned b2w, unsigned b3w,
          f16x8 a1c0, f16x8 a1c1, f32x16 biasv, f32x16 w2v, float halfb2) {
    V4 bx;
    bx.u[0] = b0w; bx.u[1] = b1w; bx.u[2] = b2w; bx.u[3] = b3w;

    f32x16 d;
#pragma unroll
    for (int r = 0; r < 16; ++r) d[r] = 0.0f;
    d = __builtin_amdgcn_mfma_f32_32x32x16_f16(a0, bx.v, d, 0, 0, 0);

    // Lane (g,c5) holds pre-act of h(r,g) = (r&3)+8*(r>>2)+4g for sample col c5.
    // tanh + pack pairs; words STAY in this lane (W1 frags absorb the permutation).
    unsigned p[8];
#pragma unroll
    for (int j = 0; j < 8; ++j)
        p[j] = pk(fast_tanh(d[2 * j]), fast_tanh(d[2 * j + 1]));

    V4 bf0, bf1;
#pragma unroll
    for (int m = 0; m < 4; ++m) { bf0.u[m] = p[m]; bf1.u[m] = p[4 + m]; }

    f32x16 e = biasv;   // C-init carries b1; no per-element movs
    e = __builtin_amdgcn_mfma_f32_32x32x16_f16(a1c0, bf0.v, e, 0, 0, 0);
    e = __builtin_amdgcn_mfma_f32_32x32x16_f16(a1c1, bf1.v, e, 0, 0, 0);

    // L2 partial: this lane's 16 h'-values; partner half-wave holds the other 16.
    float part = halfb2;
#pragma unroll
    for (int r = 0; r < 16; ++r)
        part = __builtin_fmaf(w2v[r], fast_tanh(e[r]), part);
    return part;
}

extern "C" __global__ void __launch_bounds__(256)
mlp_mfma(const float* __restrict__ q,  const float* __restrict__ w0,
         const float* __restrict__ b0, const float* __restrict__ w1,
         const float* __restrict__ b1, const float* __restrict__ w2,
         const float* __restrict__ b2, float* __restrict__ out)
{
    const int  l   = threadIdx.x & 63;
    const int  c5  = l & 31;
    const bool hi  = (l >= 32);
    const int  g   = hi ? 1 : 0;
    const int  wid = blockIdx.x * 4 + (threadIdx.x >> 6);

    // ---- setup: all per-lane constants as named vector registers ----
    f16x8 a0lo, a0hi;
    {   // L0 A-frags: row c5 of W0 (7 cols) + b0 folded at k=7 (ones-row in B).
        const float* w0r = w0 + c5 * 7;
        V4 t, z;
        t.u[0] = pk(w0r[0], w0r[1]);
        t.u[1] = pk(w0r[2], w0r[3]);
        t.u[2] = pk(w0r[4], w0r[5]);
        t.u[3] = pk(w0r[6], b0[c5]);
        z.u[0] = z.u[1] = z.u[2] = z.u[3] = 0u;
        a0lo = hi ? z.v : t.v;   // weights in g0 half -> consumes tile0 B
        a0hi = hi ? t.v : z.v;   // weights in g1 half -> consumes tile1 B
    }
    f16x8 a1c0, a1c1;
    {   // L1 A-frags, column-permuted to match in-place z0 layout:
        //   A_c[row=c5][slot=8g+j] = W1[c5][16c + 4g + (j&3) + 8*(j>>2)]
        const float* wr = w1 + c5 * 32 + 4 * g;
        V4 t;
        t.u[0] = pk(wr[0], wr[1]);   t.u[1] = pk(wr[2],  wr[3]);
        t.u[2] = pk(wr[8], wr[9]);   t.u[3] = pk(wr[10], wr[11]);
        a1c0 = t.v;
        t.u[0] = pk(wr[16], wr[17]); t.u[1] = pk(wr[18], wr[19]);
        t.u[2] = pk(wr[24], wr[25]); t.u[3] = pk(wr[26], wr[27]);
        a1c1 = t.v;
    }
    f32x16 biasv, w2v;
#pragma unroll
    for (int r = 0; r < 16; ++r) {
        const int h = (r & 3) + 8 * (r >> 2) + 4 * g;
        biasv[r] = b1[h];
        w2v[r]   = w2[h];
    }
    const float halfb2 = 0.5f * b2[0];

    // ---- main loop, software-pipelined input loads ----
    int tile = wid;
    float x[7];
    {
        const float* qp0 = q + (size_t)(tile * 64 + l) * 7;
#pragma unroll
        for (int k = 0; k < 7; ++k) x[k] = qp0[k];
    }

#pragma unroll 1
    for (int it = 0; it < ITERS; ++it) {
        const int base = tile * 64;
        const int next = tile + NWAVES;

        unsigned xp[4] = { pk(x[0], x[1]), pk(x[2], x[3]),
                           pk(x[4], x[5]), pk(x[6], 1.0f) };

        // Prefetch next iteration's sample NOW; drains under the compute below.
        // Last iter re-reads the current tile (L1-hit, values unused).
        const int pfTile = (it + 1 < ITERS) ? next : tile;
        float xn[7];
        {
            const float* qn = q + (size_t)(pfTile * 64 + l) * 7;
#pragma unroll
            for (int k = 0; k < 7; ++k) xn[k] = qn[k];
        }

        // tile0 B: g0 lanes supply k=0..7, g1 pad; tile1 B: g1 supply, g0 pad.
        unsigned bx0[4], bx1[4];
#pragma unroll
        for (int m = 0; m < 4; ++m) {
            bx0[m] = hi ? 0u : xp[m];
            bx1[m] = hi ? xp[m] : 0u;
        }

        float p0 = eval_tile(a0lo, bx0[0], bx0[1], bx0[2], bx0[3],
                             a1c0, a1c1, biasv, w2v, halfb2);
        float p1 = eval_tile(a0hi, bx1[0], bx1[1], bx1[2], bx1[3],
                             a1c0, a1c1, biasv, w2v, halfb2);

        // Pair-sum: keep own tile's partial, hand the other to the partner.
        float keep = hi ? p1 : p0;
        float send = hi ? p0 : p1;
        out[base + l] = keep + __shfl_xor(send, 32);

#pragma unroll
        for (int k = 0; k < 7; ++k) x[k] = xn[k];
        tile = next;
    }
}

extern "C" void kernel_launch(void* const* d_in, const int* in_sizes, int n_in,
                              void* d_out, int out_size, void* d_ws, size_t ws_size,
                              hipStream_t stream) {
    const float* q  = (const float*)d_in[0];
    const float* w0 = (const float*)d_in[1];
    const float* b0 = (const float*)d_in[2];
    const float* w1 = (const float*)d_in[3];
    const float* b1 = (const float*)d_in[4];
    const float* w2 = (const float*)d_in[5];
    const float* b2 = (const float*)d_in[6];
    float* out = (float*)d_out;

    hipLaunchKernelGGL(mlp_mfma, dim3(NBLK), dim3(256), 0, stream,
                       q, w0, b0, w1, b1, w2, b2, out);
}